// Round 3
// baseline (99.529 us; speedup 1.0000x reference)
//
#include <hip/hip_runtime.h>
#include <math.h>

// CropProposals: 3D ROI adaptive 2x2x2 max-pool.
// fm: (4,64,24,24,24) f32, corners: (4,64,2,3) f32 -> out: (4,64,64,2,2,2) f32
//
// Two-phase plan:
//  K1: transpose fm[b][c][s] -> ws[b][s][c]  (s = x*576+y*24+z, c contiguous)
//  K2: one wave per (b,n,bin). lane = (zphase 0..3) x (channel-quad 0..15);
//      each lane float4-loads 4 channels of one voxel -> every wave-load is
//      64x16B fully coalesced, and the box walk is plain nested loops (no
//      div/mod at all). Bins may overlap (bin_hi = lo+((k+1)*n+1)//2), so
//      each bin reduces its own range. Final reduce: shfl_xor over the 4
//      z-phase groups only.

#define SPAT 13824  // 24*24*24

__global__ __launch_bounds__(256) void transpose_kernel(
    const float* __restrict__ fm, float* __restrict__ ws)
{
    __shared__ float tile[64][65];            // pad -> conflict-free both ways
    const int b  = blockIdx.y;
    const int s0 = blockIdx.x * 64;
    const int t  = threadIdx.x;
    const int sl = t & 63;
    const int r0 = t >> 6;                    // 0..3

    const float* src = fm + (size_t)b * 64 * SPAT;
#pragma unroll
    for (int p = 0; p < 16; ++p) {
        const int cl = r0 * 16 + p;           // channel row
        tile[cl][sl] = src[(size_t)cl * SPAT + s0 + sl];   // 256B/wave, coalesced
    }
    __syncthreads();
    float* dst = ws + ((size_t)b * SPAT + s0) * 64;
#pragma unroll
    for (int p = 0; p < 16; ++p) {
        const int srow = r0 * 16 + p;         // spatial row
        dst[(size_t)srow * 64 + sl] = tile[sl][srow];      // 256B/wave, coalesced
    }
}

__device__ __forceinline__ float4 fmax4(float4 a, float4 b) {
    return make_float4(fmaxf(a.x, b.x), fmaxf(a.y, b.y),
                       fmaxf(a.z, b.z), fmaxf(a.w, b.w));
}

__global__ __launch_bounds__(256) void pool_kernel(
    const float* __restrict__ corners, const float* __restrict__ ws,
    float* __restrict__ out)
{
    const int task = blockIdx.x * 4 + (threadIdx.x >> 6);  // (bn, bin), 0..2047
    const int bin  = task & 7;                // kx*4 + ky*2 + kz
    const int bn   = task >> 3;               // b*64 + n
    const int b    = bn >> 6;
    const int lane = threadIdx.x & 63;
    const int cg   = lane >> 4;               // z-phase 0..3
    const int cq   = lane & 15;               // channel quad: ch 4*cq..4*cq+3
    const int ks[3] = { (bin >> 2) & 1, (bin >> 1) & 1, bin & 1 };

    // Per-axis bin range, exactly mirroring the reference fp32 arithmetic.
    int s0a[3], s1a[3];
#pragma unroll
    for (int a = 0; a < 3; ++a) {
        float LL = corners[bn * 6 + a] * 0.25f;
        LL = fminf(fmaxf(LL, 0.0f), 21.0f);
        float UR = corners[bn * 6 + 3 + a] * 0.25f;
        UR = (UR - LL >= 2.0f) ? UR : (LL + 2.0f);
        UR = fminf(fmaxf(UR, 2.0f), 23.0f);
        const int lo = (int)floorf(LL);
        const int nn = (int)floorf(UR) - lo;  // 2..23
        s0a[a] = lo + ((ks[a] * nn) >> 1);
        s1a[a] = lo + (((ks[a] + 1) * nn + 1) >> 1);
    }

    const float4* base = (const float4*)(ws) + (size_t)b * SPAT * 16 + cq;

    float4 m = make_float4(-INFINITY, -INFINITY, -INFINITY, -INFINITY);
    for (int x = s0a[0]; x < s1a[0]; ++x) {
        const int rx = x * 576;
        for (int y = s0a[1]; y < s1a[1]; ++y) {
            const int srow = rx + y * 24;
            for (int z = s0a[2] + cg; z < s1a[2]; z += 4) {
                m = fmax4(m, base[(size_t)(srow + z) * 16]);  // 1KB/wave, coalesced
            }
        }
    }

    // Combine the 4 z-phase groups (lanes l, l+16, l+32, l+48).
#pragma unroll
    for (int off = 16; off < 64; off <<= 1) {
        m.x = fmaxf(m.x, __shfl_xor(m.x, off));
        m.y = fmaxf(m.y, __shfl_xor(m.y, off));
        m.z = fmaxf(m.z, __shfl_xor(m.z, off));
        m.w = fmaxf(m.w, __shfl_xor(m.w, off));
    }

    if (lane < 16) {
        float* o = out + ((size_t)bn * 64 + 4 * cq) * 8 + bin;
        o[0]  = m.x;   // channel 4*cq
        o[8]  = m.y;   // channel 4*cq+1
        o[16] = m.z;
        o[24] = m.w;
    }
}

extern "C" void kernel_launch(void* const* d_in, const int* in_sizes, int n_in,
                              void* d_out, int out_size, void* d_ws, size_t ws_size,
                              hipStream_t stream)
{
    const float* fm      = (const float*)d_in[0];
    const float* corners = (const float*)d_in[1];
    float* out           = (float*)d_out;
    float* ws            = (float*)d_ws;      // 4*13824*64*4B = 14.2 MB used

    dim3 tgrid(SPAT / 64, 4);                 // 216 x 4 tiles
    transpose_kernel<<<tgrid, 256, 0, stream>>>(fm, ws);

    pool_kernel<<<512, 256, 0, stream>>>(corners, ws, out);  // 2048 waves
}

// Round 4
// 69.377 us; speedup vs baseline: 1.4346x; 1.4346x over previous
//
#include <hip/hip_runtime.h>
#include <math.h>

// CropProposals: 3D ROI adaptive 2x2x2 max-pool.
// fm: (4,64,24,24,24) f32, corners: (4,64,2,3) f32 -> out: (4,64,64,2,2,2) f32
//
// Single kernel. One block per (b,c) channel volume (256 blocks, 512 thr):
//   1. Stage the 54KB volume into LDS with coalesced float4 loads (fm is
//      L3-resident from the harness input restore -> ~1-2us aggregate).
//   2. 8 waves x 8 proposals each: lanes split 8 bins x 8 sub-lanes (bins may
//      OVERLAP: bin_hi = lo+((k+1)*n+1)//2, bin_lo = lo+k*n//2, so each bin
//      reduces its own range). Voxel walk uses exact magic-multiply division
//      (M = 2^19/d + 1, exact since i*d <= 1727*12 < 2^19). All gather
//      traffic is LDS (ds_read ~6cyc) instead of scattered global.
//   3. shfl_xor reduce over the 8-lane sub-group, funnel bins to lanes 0..7,
//      one 32B store per proposal.

#define SPAT 13824  // 24*24*24

__global__ __launch_bounds__(512) void crop_pool_kernel(
    const float* __restrict__ fm,
    const float* __restrict__ corners,
    float* __restrict__ out)
{
    __shared__ float sv[SPAT];            // 55296 B
    const int blk = blockIdx.x;           // b*64 + c
    const int b   = blk >> 6;
    const int c   = blk & 63;
    const int t   = threadIdx.x;          // 0..511

    // ---- stage: whole channel volume, coalesced float4 ----
    {
        const float4* src = (const float4*)(fm + (size_t)blk * SPAT);
        float4* dst = (float4*)sv;
#pragma unroll
        for (int p = 0; p < 7; ++p) {     // 7*512 = 3584 >= 3456
            const int i = p * 512 + t;
            if (i < SPAT / 4) dst[i] = src[i];
        }
    }
    __syncthreads();

    const int wid  = t >> 6;              // 0..7
    const int lane = t & 63;
    const int bin  = lane >> 3;           // kx*4 + ky*2 + kz
    const int sub  = lane & 7;
    const int ks[3] = { (bin >> 2) & 1, (bin >> 1) & 1, bin & 1 };

    for (int p = 0; p < 8; ++p) {
        const int n  = wid * 8 + p;
        const int bn = b * 64 + n;

        // Per-axis bin range, exactly mirroring the reference fp32 arithmetic.
        int s0[3], s1[3];
#pragma unroll
        for (int a = 0; a < 3; ++a) {
            float LL = corners[bn * 6 + a] * 0.25f;
            LL = fminf(fmaxf(LL, 0.0f), 21.0f);
            float UR = corners[bn * 6 + 3 + a] * 0.25f;
            UR = (UR - LL >= 2.0f) ? UR : (LL + 2.0f);
            UR = fminf(fmaxf(UR, 2.0f), 23.0f);
            const int lo = (int)floorf(LL);
            const int nn = (int)floorf(UR) - lo;   // 2..23
            s0[a] = lo + ((ks[a] * nn) >> 1);
            s1[a] = lo + (((ks[a] + 1) * nn + 1) >> 1);
        }
        const unsigned ny   = (unsigned)(s1[1] - s0[1]);   // 1..12
        const unsigned nz   = (unsigned)(s1[2] - s0[2]);   // 1..12
        const unsigned nvox = (unsigned)(s1[0] - s0[0]) * ny * nz;  // <= 1728
        const unsigned Mz = (1u << 19) / nz + 1;
        const unsigned My = (1u << 19) / ny + 1;
        const int boff = (s0[0] * 24 + s0[1]) * 24 + s0[2];

        auto voxel = [&](unsigned i) -> float {
            unsigned q = (i * Mz) >> 19;   // q = x*ny + y
            unsigned z = i - q * nz;
            unsigned x = (q * My) >> 19;
            unsigned y = q - x * ny;
            return sv[boff + (int)(x * 576u + y * 24u + z)];
        };

        float m0 = -INFINITY, m1 = -INFINITY, m2 = -INFINITY, m3 = -INFINITY;
        unsigned i = sub;
        for (; i + 24 < nvox; i += 32) {   // 4 LDS reads in flight
            m0 = fmaxf(m0, voxel(i));
            m1 = fmaxf(m1, voxel(i + 8));
            m2 = fmaxf(m2, voxel(i + 16));
            m3 = fmaxf(m3, voxel(i + 24));
        }
        for (; i < nvox; i += 8)
            m0 = fmaxf(m0, voxel(i));
        float m = fmaxf(fmaxf(m0, m1), fmaxf(m2, m3));

        // Reduce the 8-lane sub-group (xor 1,2,4 stay within the bin group).
#pragma unroll
        for (int off = 1; off < 8; off <<= 1)
            m = fmaxf(m, __shfl_xor(m, off));

        // Funnel the 8 bin maxes to lanes 0..7 -> one 32B store.
        const float v = __shfl(m, (lane & 7) << 3);
        if (lane < 8)
            out[((size_t)(bn * 64 + c)) * 8 + lane] = v;
    }
}

extern "C" void kernel_launch(void* const* d_in, const int* in_sizes, int n_in,
                              void* d_out, int out_size, void* d_ws, size_t ws_size,
                              hipStream_t stream)
{
    const float* fm      = (const float*)d_in[0];
    const float* corners = (const float*)d_in[1];
    float* out           = (float*)d_out;

    // 256 blocks (one per (b,c)), 8 waves each.
    crop_pool_kernel<<<256, 512, 0, stream>>>(fm, corners, out);
}